// Round 3
// baseline (279.749 us; speedup 1.0000x reference)
//
#include <hip/hip_runtime.h>

using bf16_t = __bf16;
typedef __bf16 bf16x4 __attribute__((ext_vector_type(4)));
typedef __bf16 bf16x8 __attribute__((ext_vector_type(8)));
typedef float floatx4 __attribute__((ext_vector_type(4)));

#define MFMA_BF16(a, b, c) __builtin_amdgcn_mfma_f32_16x16x32_bf16((a), (b), (c), 0, 0, 0)

__device__ __forceinline__ void async_ld16(bf16_t* lds_dst, const bf16_t* g_src) {
    __builtin_amdgcn_global_load_lds(
        (const __attribute__((address_space(1))) void*)g_src,
        (__attribute__((address_space(3))) void*)lds_dst, 16, 0, 0);
}

// ---------------------------------------------------------------------------
// fp32 -> bf16 cast, 8 elements/thread
// ---------------------------------------------------------------------------
__global__ __launch_bounds__(256) void cast_bf16(const float* __restrict__ src,
                                                 bf16_t* __restrict__ dst, int n8) {
    int i = blockIdx.x * 256 + threadIdx.x;
    if (i < n8) {
        const floatx4 a = *(const floatx4*)(src + (size_t)i * 8);
        const floatx4 b = *(const floatx4*)(src + (size_t)i * 8 + 4);
        bf16x8 r;
        r[0] = (bf16_t)a[0]; r[1] = (bf16_t)a[1]; r[2] = (bf16_t)a[2]; r[3] = (bf16_t)a[3];
        r[4] = (bf16_t)b[0]; r[5] = (bf16_t)b[1]; r[6] = (bf16_t)b[2]; r[7] = (bf16_t)b[3];
        *(bf16x8*)(dst + (size_t)i * 8) = r;
    }
}

// ---------------------------------------------------------------------------
// lam = exp(sum(lq1*lk1)) - exp(sum(lq2*lk2)) + 0.2   (DEPTH=0)
// ---------------------------------------------------------------------------
__global__ void lam_kernel(const float* lq1, const float* lq2,
                           const float* lk1, const float* lk2, float* lamp) {
    int l = threadIdx.x;
    float p1 = lq1[l] * lk1[l];
    float p2 = lq2[l] * lk2[l];
    #pragma unroll
    for (int d = 1; d < 64; d <<= 1) {
        p1 += __shfl_xor(p1, d);
        p2 += __shfl_xor(p2, d);
    }
    if (l == 0) *lamp = expf(p1) - expf(p2) + 0.2f;
}

// ---------------------------------------------------------------------------
// GEMM (bf16): C[m][n] = sum_k A[m][k]*B[n][k]. BK=32, global_load_lds
// width-16 staging into [row][32] LDS, 16x16x32 MFMA, 2x2 waves.
// QKV_EPI routes into Qb/Kb ([inst][h][n][64], unrotated) and Vt ([h*128+vc][n]).
// ---------------------------------------------------------------------------
template <int BM, int BN, bool QKV_EPI, typename TC>
__global__ __launch_bounds__(256) void gemm_bt(const bf16_t* __restrict__ A,
                                               const bf16_t* __restrict__ B,
                                               TC* __restrict__ C,
                                               bf16_t* __restrict__ Qb,
                                               bf16_t* __restrict__ Kb,
                                               bf16_t* __restrict__ Vt,
                                               int M, int N, int K) {
    constexpr int BK = 32;
    __shared__ __align__(16) bf16_t As[BM * BK];
    __shared__ __align__(16) bf16_t Bs[BN * BK];
    const int t = threadIdx.x;
    const int lane = t & 63, wave = t >> 6;
    const int q4 = lane >> 4, m16 = lane & 15;
    const int mblk = blockIdx.y * BM, nblk = blockIdx.x * BN;
    const int wr = wave >> 1, wc = wave & 1;
    constexpr int WM = BM / 2, WN = BN / 2;
    constexpr int NI = WM / 16, NJ = WN / 16;
    constexpr int AR = BM * BK / 2048;
    constexpr int BR = BN * BK / 2048;

    floatx4 acc[NI][NJ] = {};

    for (int k0 = 0; k0 < K; k0 += BK) {
        __syncthreads();
        #pragma unroll
        for (int rr = 0; rr < AR; ++rr) {
            int f = rr * 256 + t;
            async_ld16(&As[f * 8], &A[(size_t)(mblk + (f >> 2)) * K + k0 + (f & 3) * 8]);
        }
        #pragma unroll
        for (int rr = 0; rr < BR; ++rr) {
            int f = rr * 256 + t;
            async_ld16(&Bs[f * 8], &B[(size_t)(nblk + (f >> 2)) * K + k0 + (f & 3) * 8]);
        }
        __syncthreads();

        bf16x8 a[NI], b[NJ];
        #pragma unroll
        for (int i = 0; i < NI; ++i)
            a[i] = *(const bf16x8*)&As[(wr * WM + i * 16 + m16) * 32 + q4 * 8];
        #pragma unroll
        for (int j = 0; j < NJ; ++j)
            b[j] = *(const bf16x8*)&Bs[(wc * WN + j * 16 + m16) * 32 + q4 * 8];
        #pragma unroll
        for (int i = 0; i < NI; ++i)
            #pragma unroll
            for (int j = 0; j < NJ; ++j)
                acc[i][j] = MFMA_BF16(a[i], b[j], acc[i][j]);
    }

    #pragma unroll
    for (int i = 0; i < NI; ++i)
        #pragma unroll
        for (int j = 0; j < NJ; ++j) {
            int n = nblk + wc * WN + j * 16 + m16;
            int mbase = mblk + wr * WM + i * 16 + q4 * 4;
            if constexpr (QKV_EPI) {
                int comp = n >> 10, h = (n >> 6) & 15, e = n & 63;
                if (comp < 2) {
                    #pragma unroll
                    for (int r = 0; r < 4; ++r)
                        Qb[(size_t)((comp * 16 + h) * 2048 + mbase + r) * 64 + e] =
                            (bf16_t)acc[i][j][r];
                } else if (comp < 4) {
                    #pragma unroll
                    for (int r = 0; r < 4; ++r)
                        Kb[(size_t)(((comp - 2) * 16 + h) * 2048 + mbase + r) * 64 + e] =
                            (bf16_t)acc[i][j][r];
                } else {
                    bf16x4 pv;
                    #pragma unroll
                    for (int r = 0; r < 4; ++r) pv[r] = (bf16_t)acc[i][j][r];
                    *(bf16x4*)&Vt[(size_t)(h * 128 + (comp - 4) * 64 + e) * 2048 + mbase] = pv;
                }
            } else {
                #pragma unroll
                for (int r = 0; r < 4; ++r)
                    C[(size_t)(mbase + r) * N + n] = (TC)acc[i][j][r];
            }
        }
}

// ---------------------------------------------------------------------------
// In-place rotary on Qb/Kb [inst][h][n][64]
// ---------------------------------------------------------------------------
__global__ __launch_bounds__(256) void rotary_inplace(bf16_t* __restrict__ Qb,
                                                      bf16_t* __restrict__ Kb) {
    int t = blockIdx.x * 256 + threadIdx.x;
    int e = t & 63, h = (t >> 6) & 15, n = t >> 10;
    float invf = exp2f(-(float)e * (13.287712379549449f / 64.0f));
    float ang = (float)n * invf;
    float s, c;
    sincosf(ang, &s, &c);
    int off = (h * 2048 + n) * 64 + e;
    float q1 = (float)Qb[off], q2 = (float)Qb[off + 2097152];
    Qb[off]           = (bf16_t)(q1 * c - q2 * s);
    Qb[off + 2097152] = (bf16_t)(q2 * c + q1 * s);
    float k1 = (float)Kb[off], k2 = (float)Kb[off + 2097152];
    Kb[off]           = (bf16_t)(k1 * c - k2 * s);
    Kb[off + 2097152] = (bf16_t)(k2 * c + k1 * s);
}

// ---------------------------------------------------------------------------
// Differential flash attention, v9 = LDS-traffic restructure.
// LDS-bandwidth analysis of v8: 26 ds_read_b128/wave-iter = ~67us of LDS
// port time. v9 cuts to 12 reads + 4 b64 writes:
//  - K bypasses LDS entirely: per-wave global->VGPR fragment loads (the
//    staging per-lane address IS the fragment address), reg-double-buffered
//    one iteration ahead. K LDS amplification was 1x, so zero cost.
//  - Swapped QK^T: mfma(K,Q) -> S^T[key][qrow]. Wave (comp,kq) covers
//    16 keys x 64 qrows (Q persistent in 8 bf16x8 regs). Row sums become
//    in-register scalar adds (ones-MFMA deleted).
//  - P packed to bf16x4, stored via 4 ds_write_b64 into unit-swizzled
//    Pf regions [comp][qtile][kc] (phys = U ^ (U>>4); reader uses lane^q4).
//  - PV register blocking 32q x 64vc per wave: 4 P reads + 8 V reads
//    (was 2 + 16).
//  - 2 barriers/iter (P now cross-wave). LDS 48 KB: V dbuf 32 + Pf 16.
//  - Epilogue: comp1 publishes raw O via Ff (V area); comp0 reads both
//    row-sum sets from Rs (Pf area) and combines.
// ---------------------------------------------------------------------------
__global__ __launch_bounds__(512, 4) void flash_diff(const bf16_t* __restrict__ Qb,
                                                     const bf16_t* __restrict__ Kb,
                                                     const bf16_t* __restrict__ Vt,
                                                     const float* __restrict__ lamp,
                                                     bf16_t* __restrict__ Ao) {
    constexpr int N = 2048, BN = 64, NT = N / BN;  // 32 chunks
    __shared__ __align__(16) bf16_t smem[24576];   // 48 KB
    bf16_t* Pf = smem + 16384;                     // [2c][4 qtile][2 kc] x 512
    const int t = threadIdx.x, lane = t & 63, w = t >> 6;   // w in 0..7
    const int comp = w >> 2, sub = w & 3;
    const int q4 = lane >> 4, m16 = lane & 15;
    // XCD-clustered decode: heads 2x,2x+1 per XCD -> K/V L2-resident.
    const int Lb = blockIdx.x;
    const int virt = (Lb & 7) * 64 + (Lb >> 3);
    const int h = virt >> 5, qt = virt & 31;
    const float lam = *lamp;
    const float cexp = 0.125f * 1.4426950408889634f;  // scale * log2(e)

    const int kq = sub;                  // QK role: keys 16*kq..+15
    const int aa = sub >> 1, bb = sub & 1;  // PV role: q-half, vc-half

    // Q fragments (B-operand: col=m16 -> qrow, k=q4*8+j -> e), persistent.
    bf16x8 qf[4][2];
    #pragma unroll
    for (int qq = 0; qq < 4; ++qq)
        #pragma unroll
        for (int e = 0; e < 2; ++e)
            qf[qq][e] = *(const bf16x8*)&Qb[(size_t)((comp * 16 + h) * 2048 +
                             qt * 64 + qq * 16 + m16) * 64 + e * 32 + q4 * 8];

    // K fragment global base (A-operand: row=m16 -> key, k=q4*8+j -> e).
    const bf16_t* kbase = &Kb[(size_t)((comp * 16 + h) * 2048 + 16 * kq + m16) * 64 + q4 * 8];
    bf16x8 kcur0 = *(const bf16x8*)(kbase);
    bf16x8 kcur1 = *(const bf16x8*)(kbase + 32);
    bf16x8 knext0, knext1;

    // P-store offset: writer element (key16=16kk+4q4+r, qrow=m16) ->
    // A-frag unit U=(2kk+(q4>>1))*16+m16, dwords (2q4)&3..+1; phys=U^(U>>4).
    const int uhi = 2 * (kq & 1) + (q4 >> 1);
    const int poff = (uhi * 16 + (m16 ^ uhi)) * 8 + (q4 & 1) * 4;  // bf16 units
    const int kc_w = kq >> 1;

    auto stageV = [&](bf16_t* Vd, int k0) {
        #pragma unroll
        for (int rr = 0; rr < 2; ++rr) {
            int idx = w * 2 + rr;               // 16 V spans, 2 per wave
            int tt = idx >> 1, half = idx & 1;  // span (vc=16tt+m16, key=32half+8q4+j)
            async_ld16(&Vd[idx * 512],
                       &Vt[(size_t)(h * 128 + tt * 16 + m16) * 2048 + k0 + half * 32 + q4 * 8]);
        }
    };
    stageV(smem, 0);  // prologue: chunk 0 -> buf 0

    floatx4 O[2][4] = {};
    float rs[4] = {};

    #pragma unroll 2
    for (int it = 0; it < NT; ++it) {
        bf16_t* Vb = smem + (it & 1) * 8192;
        __syncthreads();  // V[cur] staged+drained; prev iter's P/V reads done

        if (it + 1 < NT) {  // K prefetch for next chunk (global -> reg)
            const bf16_t* kb = kbase + (size_t)(it + 1) * 4096;
            knext0 = *(const bf16x8*)(kb);
            knext1 = *(const bf16x8*)(kb + 32);
        }

        // ---- swapped QK^T: S^T[key][qrow]; exp2; pack; b64 store ----
        __builtin_amdgcn_s_setprio(1);
        #pragma unroll
        for (int qq = 0; qq < 4; ++qq) {
            floatx4 s = {};
            s = MFMA_BF16(kcur0, qf[qq][0], s);
            s = MFMA_BF16(kcur1, qf[qq][1], s);
            __builtin_amdgcn_s_setprio(0);
            float p0 = exp2f(s[0] * cexp), p1 = exp2f(s[1] * cexp);
            float p2 = exp2f(s[2] * cexp), p3 = exp2f(s[3] * cexp);
            rs[qq] += (p0 + p1) + (p2 + p3);
            bf16x4 wv;
            wv[0] = (bf16_t)p0; wv[1] = (bf16_t)p1; wv[2] = (bf16_t)p2; wv[3] = (bf16_t)p3;
            *(bf16x4*)&Pf[((comp * 4 + qq) * 2 + kc_w) * 512 + poff] = wv;
            __builtin_amdgcn_s_setprio(1);
        }
        __builtin_amdgcn_s_setprio(0);
        __syncthreads();  // P visible to all waves

        if (it + 1 < NT) stageV(smem + (((it & 1) ^ 1) * 8192), (it + 1) * BN);

        // ---- PV: 32q x 64vc per wave; 4 P reads + 8 V reads, 16 MFMA ----
        const int ur = (lane ^ q4) * 8;
        bf16x8 pf00 = *(const bf16x8*)&Pf[((comp * 4 + 2 * aa + 0) * 2 + 0) * 512 + ur];
        bf16x8 pf01 = *(const bf16x8*)&Pf[((comp * 4 + 2 * aa + 0) * 2 + 1) * 512 + ur];
        bf16x8 pf10 = *(const bf16x8*)&Pf[((comp * 4 + 2 * aa + 1) * 2 + 0) * 512 + ur];
        bf16x8 pf11 = *(const bf16x8*)&Pf[((comp * 4 + 2 * aa + 1) * 2 + 1) * 512 + ur];
        __builtin_amdgcn_s_setprio(1);
        #pragma unroll
        for (int vv = 0; vv < 4; ++vv) {
            const bf16x8 vf0 = *(const bf16x8*)&Vb[((bb * 4 + vv) * 2 + 0) * 512 + lane * 8];
            const bf16x8 vf1 = *(const bf16x8*)&Vb[((bb * 4 + vv) * 2 + 1) * 512 + lane * 8];
            O[0][vv] = MFMA_BF16(pf00, vf0, O[0][vv]);
            O[0][vv] = MFMA_BF16(pf01, vf1, O[0][vv]);
            O[1][vv] = MFMA_BF16(pf10, vf0, O[1][vv]);
            O[1][vv] = MFMA_BF16(pf11, vf1, O[1][vv]);
        }
        __builtin_amdgcn_s_setprio(0);
        kcur0 = knext0;
        kcur1 = knext1;
    }

    // ---- row-sum reduce: over q4-lane groups, then cross-wave via LDS ----
    #pragma unroll
    for (int qq = 0; qq < 4; ++qq) {
        rs[qq] += __shfl_xor(rs[qq], 16);
        rs[qq] += __shfl_xor(rs[qq], 32);
    }
    __syncthreads();  // last iter's Pf/V reads complete; LDS reusable
    float* Rs = (float*)Pf;    // [2c][4 qq][16 m16][4 kq]
    if (q4 == 0) {
        #pragma unroll
        for (int qq = 0; qq < 4; ++qq)
            Rs[((comp * 4 + qq) * 16 + m16) * 4 + kq] = rs[qq];
    }
    float* Ff = (float*)smem;  // [aa*2+bb] regions of 2048 f32 (V area, 32 KB)
    if (comp == 1) {
        #pragma unroll
        for (int i = 0; i < 2; ++i)
            #pragma unroll
            for (int vv = 0; vv < 4; ++vv)
                *(floatx4*)&Ff[(aa * 2 + bb) * 2048 + ((i * 4 + vv) * 16 + m16) * 16 + q4 * 4] =
                    O[i][vv];
    }
    __syncthreads();
    if (comp == 0) {
        float inv0[2][4], inv1l[2][4];
        #pragma unroll
        for (int i = 0; i < 2; ++i)
            #pragma unroll
            for (int r = 0; r < 4; ++r) {
                const floatx4 s0 = *(const floatx4*)&Rs[((2 * aa + i) * 16 + q4 * 4 + r) * 4];
                const floatx4 s1 = *(const floatx4*)&Rs[((4 + 2 * aa + i) * 16 + q4 * 4 + r) * 4];
                inv0[i][r] = 1.0f / ((s0[0] + s0[1]) + (s0[2] + s0[3]));
                inv1l[i][r] = lam / ((s1[0] + s1[1]) + (s1[2] + s1[3]));
            }
        #pragma unroll
        for (int i = 0; i < 2; ++i)
            #pragma unroll
            for (int vv = 0; vv < 4; ++vv) {
                const floatx4 o1 = *(const floatx4*)&Ff[(aa * 2 + bb) * 2048 +
                                       ((i * 4 + vv) * 16 + m16) * 16 + q4 * 4];
                #pragma unroll
                for (int r = 0; r < 4; ++r) {
                    float val = O[i][vv][r] * inv0[i][r] - o1[r] * inv1l[i][r];
                    Ao[(size_t)(qt * 64 + (2 * aa + i) * 16 + q4 * 4 + r) * 2048 +
                       h * 128 + (bb * 4 + vv) * 16 + m16] = (bf16_t)val;
                }
            }
    }
}

// ---------------------------------------------------------------------------
extern "C" void kernel_launch(void* const* d_in, const int* in_sizes, int n_in,
                              void* d_out, int out_size, void* d_ws, size_t ws_size,
                              hipStream_t stream) {
    const float* x     = (const float*)d_in[0];
    const float* Wqkv  = (const float*)d_in[1];
    const float* Wproj = (const float*)d_in[2];
    const float* lq1   = (const float*)d_in[3];
    const float* lq2   = (const float*)d_in[4];
    const float* lk1   = (const float*)d_in[5];
    const float* lk2   = (const float*)d_in[6];
    float* out = (float*)d_out;

    char* ws = (char*)d_ws;
    bf16_t* xb     = (bf16_t*)(ws);               //  4,194,304 B
    bf16_t* Ao     = (bf16_t*)(ws);               //  aliases xb/Wqkvb (dead post-QKV)
    bf16_t* Wqkvb  = (bf16_t*)(ws + 4194304);     // 12,582,912 B
    bf16_t* Wprojb = (bf16_t*)(ws + 16777216);    //  4,194,304 B
    bf16_t* Qb     = (bf16_t*)(ws + 20971520);    //  8,388,608 B
    bf16_t* Kb     = (bf16_t*)(ws + 29360128);    //  8,388,608 B
    bf16_t* Vt     = (bf16_t*)(ws + 37748736);    //  8,388,608 B
    float*  lamp   = (float*)(ws + 46137344);     //  4 B (total ~46.1 MB)

    lam_kernel<<<1, 64, 0, stream>>>(lq1, lq2, lk1, lk2, lamp);
    cast_bf16<<<1024, 256, 0, stream>>>(x, xb, 2048 * 1024 / 8);
    cast_bf16<<<3072, 256, 0, stream>>>(Wqkv, Wqkvb, 6144 * 1024 / 8);
    cast_bf16<<<1024, 256, 0, stream>>>(Wproj, Wprojb, 1024 * 2048 / 8);
    gemm_bt<128, 128, true, float><<<dim3(48, 16), 256, 0, stream>>>(
        xb, Wqkvb, (float*)nullptr, Qb, Kb, Vt, 2048, 6144, 1024);
    rotary_inplace<<<(2048 * 16 * 64) / 256, 256, 0, stream>>>(Qb, Kb);
    flash_diff<<<512, 512, 0, stream>>>(Qb, Kb, Vt, lamp, Ao);
    gemm_bt<128, 64, false, float><<<dim3(16, 16), 256, 0, stream>>>(
        Ao, Wprojb, out, (bf16_t*)nullptr, (bf16_t*)nullptr, (bf16_t*)nullptr,
        2048, 1024, 2048);
}